// Round 4
// baseline (577.964 us; speedup 1.0000x reference)
//
#include <hip/hip_runtime.h>

// Sinkhorn divergence (geomloss 'sinkhorn', p=2, blur=0.05, diameter=4, scaling=0.5, debias)
// B=2, N=M=4096, D=3, fp32.
// R8: persistent fusion via PLAIN launch (R7's hipLaunchCooperativeKernel produced NaN =
// kernel-never-ran / raced; cooperative launch is a stream-capture hole). Co-residency by
// construction: __launch_bounds__(512,4) -> <=128 VGPR -> 2 blocks/CU x 256 CU = 512 = grid,
// so every block is resident and the monotonic-counter barrier cannot deadlock.
// Barrier visibility: __threadfence() + device-scope atomicAdd + relaxed spin +
// __threadfence() (the classic persistent-kernel pattern); bounded spin (~1s) turns any
// residual deadlock into a finite failure instead of a harness hang.
// Hoisted across eps-iterations: B fragments (eps-independent), y loads + norms.
// Inner loop: exact 321.6us baseline form (all-EXP2 merge16, 8 MFMAs / 64 cols).

typedef __attribute__((ext_vector_type(8))) short short8;
typedef __attribute__((ext_vector_type(8))) __bf16 bf16x8;
typedef __attribute__((ext_vector_type(4))) float f32x4;
typedef __attribute__((ext_vector_type(2))) float f32x2;

#define NPT 4096
#define BLOCK 512
#define COLS 1024           // columns per block (one part)
#define GRID 512            // 8 tbl x 4 parts x 16 rowchunks
#define NLAUNCH 11
#define EXP2 __builtin_amdgcn_exp2f
#define LOG2 __builtin_amdgcn_logf
#define KLOG2E 1.4426950408889634f
#define KLN2 0.6931471805599453f

__device__ const float epsC[NLAUNCH] = {16.0f, 16.0f, 16.0f, 4.0f, 1.0f, 0.25f,
                                        0.0625f, 0.015625f, 0.00390625f, 0.0025f, 0.0025f};

__device__ inline unsigned short f2bf(float f) {
  unsigned u = __float_as_uint(f);
  return (unsigned short)((u + 0x7FFF + ((u >> 16) & 1)) >> 16);
}
__device__ inline float bf2f(unsigned short h) {
  return __uint_as_float(((unsigned)h) << 16);
}

struct PArgs {
  const float* x;
  const float* y;
  float2* P0;   // partials buffer A [8 tbl][4 part][4096] (m,s)
  float2* P1;   // partials buffer B
  float* F0;    // finalized potentials buffer A [8 tbl][4096]
  float* F1;
  unsigned* bar;  // monotonic grid-barrier counter (zeroed per launch)
};

// Monotonic-counter grid barrier. All 512 blocks are co-resident (see launch math),
// so spinning is safe. __threadfence() provides agent-scope release/acquire (L2
// writeback + invalidate across XCDs). Bounded spin avoids harness hangs.
__device__ inline void grid_barrier(unsigned* bar, unsigned target) {
  __syncthreads();
  if (threadIdx.x == 0) {
    __threadfence();
    atomicAdd(bar, 1u);   // device-scope by default on gfx950
    unsigned spins = 0;
    while (__hip_atomic_load(bar, __ATOMIC_RELAXED, __HIP_MEMORY_SCOPE_AGENT) < target) {
      __builtin_amdgcn_s_sleep(8);
      if (++spins > (1u << 22)) break;   // ~1s safety valve
    }
    __threadfence();
  }
  __syncthreads();
}

// merge 16 values into running (m,s); max3-friendly tree + packed f32x2 sub/sum.
__device__ inline void lse_merge16(float& m, float& s,
                                   f32x4 c0, f32x4 c1, f32x4 c2, f32x4 c3) {
  float t0 = fmaxf(fmaxf(c0.x, c0.y), c0.z);
  float t1 = fmaxf(fmaxf(c0.w, c1.x), c1.y);
  float t2 = fmaxf(fmaxf(c1.z, c1.w), c2.x);
  float t3 = fmaxf(fmaxf(c2.y, c2.z), c2.w);
  float t4 = fmaxf(fmaxf(c3.x, c3.y), c3.z);
  float u0 = fmaxf(fmaxf(t0, t1), c3.w);
  float u1 = fmaxf(fmaxf(t2, t3), t4);
  float cm = fmaxf(u0, u1);
  float mn = fmaxf(m, cm);
  float sc = EXP2(m - mn);                 // m=-inf first iter -> 0
  f32x2 mn2 = {mn, mn};
  f32x2 sa = {0.0f, 0.0f}, sb = {0.0f, 0.0f};
  f32x2 d;
  d = (f32x2){c0.x, c0.y} - mn2; sa += (f32x2){EXP2(d.x), EXP2(d.y)};
  d = (f32x2){c0.z, c0.w} - mn2; sb += (f32x2){EXP2(d.x), EXP2(d.y)};
  d = (f32x2){c1.x, c1.y} - mn2; sa += (f32x2){EXP2(d.x), EXP2(d.y)};
  d = (f32x2){c1.z, c1.w} - mn2; sb += (f32x2){EXP2(d.x), EXP2(d.y)};
  d = (f32x2){c2.x, c2.y} - mn2; sa += (f32x2){EXP2(d.x), EXP2(d.y)};
  d = (f32x2){c2.z, c2.w} - mn2; sb += (f32x2){EXP2(d.x), EXP2(d.y)};
  d = (f32x2){c3.x, c3.y} - mn2; sa += (f32x2){EXP2(d.x), EXP2(d.y)};
  d = (f32x2){c3.z, c3.w} - mn2; sb += (f32x2){EXP2(d.x), EXP2(d.y)};
  sa += sb;
  s = fmaf(s, sc, sa.x + sa.y);
  m = mn;
}

__global__ __launch_bounds__(BLOCK, 4) void softmin_persist(PArgs A) {
  __shared__ short8 fragA0[COLS];   // k0..7  per column
  __shared__ short8 fragA1[COLS];   // k8..15 per column

  const int bid  = blockIdx.x;
  const int tbl  = bid >> 6;          // 0..7 = task*2+batch
  const int task = tbl >> 1, batch = tbl & 1;
  const int rem  = bid & 63;
  const int part = rem >> 4;
  const int rc   = rem & 15;

  // rows[4]={x,y,x,y}; cols[4]={y,x,x,y}
  const bool rowIsX = (task == 0) | (task == 2);
  const bool colIsX = (task == 1) | (task == 2);
  const float* xp = (rowIsX ? A.x : A.y) + batch * NPT * 3;
  const float* yp = (colIsX ? A.x : A.y) + batch * NPT * 3;

  const float hc = -8.317766166719343f;   // -ln(4096)
  const int pidxA[4] = {1, 0, 2, 3};
  const int tP = pidxA[task] * 2 + batch;

  const int lane = threadIdx.x & 63;
  const int wave = threadIdx.x >> 6;
  const int q    = lane >> 4;
  const int rowbase = rc * 256 + wave * 32;

  // ---- B fragments (row side): eps-independent, build ONCE ----
  bf16x8 Bf[2];
#pragma unroll
  for (int rs = 0; rs < 2; ++rs) {
    int i = rowbase + rs * 16 + (lane & 15);
    float X0 = xp[3 * i], X1 = xp[3 * i + 1], X2 = xp[3 * i + 2];
    unsigned short xh0 = f2bf(X0), xh1 = f2bf(X1), xh2 = f2bf(X2);
    unsigned short xl0 = f2bf(X0 - bf2f(xh0));
    unsigned short xl1 = f2bf(X1 - bf2f(xh1));
    unsigned short xl2 = f2bf(X2 - bf2f(xh2));
    short8 bb = (short8)0;
    if (q == 0) {
      short8 t = {(short)xh0, (short)xh1, (short)xh2,
                  (short)xh0, (short)xh1, (short)xh2,
                  (short)xl0, (short)xl1};
      bb = t;
    } else if (q == 1) {
      short8 t = {(short)xl2, (short)0x3F80, (short)0x3F80, (short)0x3F80,
                  (short)xl0, (short)xl1, (short)xl2, 0};
      bb = t;
    }
    Bf[rs] = __builtin_bit_cast(bf16x8, bb);
  }

  // ---- per-thread column data: load ONCE, keep in registers ----
  float Y0[2], Y1[2], Y2[2], Y2N[2];
#pragma unroll
  for (int c = 0; c < 2; ++c) {
    int j = part * COLS + threadIdx.x + c * BLOCK;
    Y0[c] = yp[3 * j]; Y1[c] = yp[3 * j + 1]; Y2[c] = yp[3 * j + 2];
    Y2N[c] = 0.5f * (Y0[c] * Y0[c] + Y1[c] * Y1[c] + Y2[c] * Y2[c]);
  }

  float epsPrev = 1.0f;
  for (int L = 0; L < NLAUNCH; ++L) {
    const float eps = epsC[L];
    const int usePot  = (L >= 1);
    const int avgPrev = (L >= 2);
    const float2* Pprev = (L & 1) ? A.P0 : A.P1;
    float2*       Pcur  = (L & 1) ? A.P1 : A.P0;
    const float*  Fprev = (L & 1) ? A.F0 : A.F1;
    float*        Fcur  = (L & 1) ? A.F1 : A.F0;
    const float inv_eps = 1.0f / eps;
    const float sY = inv_eps * KLOG2E;

    // ---- staging: finalize prev-iteration potentials + build column A-fragments ----
#pragma unroll
    for (int c = 0; c < 2; ++c) {
      int jl = threadIdx.x + c * BLOCK;
      int j  = part * COLS + jl;
      float y0 = Y0[c], y1 = Y1[c], y2 = Y2[c];
      float y2n = Y2N[c];
      float pot = 0.0f;
      if (usePot) {
        float2 q0 = Pprev[(tP * 4 + 0) * NPT + j];
        float2 q1 = Pprev[(tP * 4 + 1) * NPT + j];
        float2 q2 = Pprev[(tP * 4 + 2) * NPT + j];
        float2 q3 = Pprev[(tP * 4 + 3) * NPT + j];
        float M = fmaxf(fmaxf(q0.x, q1.x), fmaxf(q2.x, q3.x));
        float S = q0.y * EXP2(q0.x - M) + q1.y * EXP2(q1.x - M)
                + q2.y * EXP2(q2.x - M) + q3.y * EXP2(q3.x - M);
        float Lg = M + LOG2(S);
        float r = y2n - epsPrev * KLN2 * Lg;
        if (avgPrev) r = 0.5f * (Fprev[tP * NPT + j] + r);
        pot = r;
        if (rc == 0) Fcur[tP * NPT + j] = pot;
      }
      float T = (hc + (pot - y2n) * inv_eps) * KLOG2E;
      float s0 = y0 * sY, s1 = y1 * sY, s2 = y2 * sY;
      unsigned short yh0 = f2bf(s0), yh1 = f2bf(s1), yh2 = f2bf(s2);
      unsigned short yl0 = f2bf(s0 - bf2f(yh0));
      unsigned short yl1 = f2bf(s1 - bf2f(yh1));
      unsigned short yl2 = f2bf(s2 - bf2f(yh2));
      unsigned short Th = f2bf(T);
      float tr = T - bf2f(Th);
      unsigned short Tm = f2bf(tr);
      tr -= bf2f(Tm);
      unsigned short Tl = f2bf(tr);
      short8 h0 = {(short)yh0, (short)yh1, (short)yh2,
                   (short)yl0, (short)yl1, (short)yl2,
                   (short)yh0, (short)yh1};
      short8 h1 = {(short)yh2, (short)Th, (short)Tm, (short)Tl,
                   (short)yl0, (short)yl1, (short)yl2, 0};
      fragA0[jl] = h0;
      fragA1[jl] = h1;
    }
    __syncthreads();

    // ---- inner loop: 4 column tiles (64 cols) per iteration, 8 MFMAs ----
    const short8* srcA = (lane & 16) ? fragA1 : fragA0;
    const int colsel = lane & 15;
    const f32x4 Z = {0.0f, 0.0f, 0.0f, 0.0f};
    short8 as0 = (short8)0, as1 = (short8)0, as2 = (short8)0, as3 = (short8)0;
    float m0 = -__builtin_inff(), s0_ = 0.0f;
    float m1 = -__builtin_inff(), s1_ = 0.0f;

    for (int jt = 0; jt < COLS / 16; jt += 4) {
      if (lane < 32) {
        as0 = srcA[(jt + 0) * 16 + colsel];
        as1 = srcA[(jt + 1) * 16 + colsel];
        as2 = srcA[(jt + 2) * 16 + colsel];
        as3 = srcA[(jt + 3) * 16 + colsel];
      }
      bf16x8 A0 = __builtin_bit_cast(bf16x8, as0);
      bf16x8 A1 = __builtin_bit_cast(bf16x8, as1);
      bf16x8 A2 = __builtin_bit_cast(bf16x8, as2);
      bf16x8 A3 = __builtin_bit_cast(bf16x8, as3);
      f32x4 c00 = __builtin_amdgcn_mfma_f32_16x16x32_bf16(A0, Bf[0], Z, 0, 0, 0);
      f32x4 c01 = __builtin_amdgcn_mfma_f32_16x16x32_bf16(A1, Bf[0], Z, 0, 0, 0);
      f32x4 c02 = __builtin_amdgcn_mfma_f32_16x16x32_bf16(A2, Bf[0], Z, 0, 0, 0);
      f32x4 c03 = __builtin_amdgcn_mfma_f32_16x16x32_bf16(A3, Bf[0], Z, 0, 0, 0);
      f32x4 c10 = __builtin_amdgcn_mfma_f32_16x16x32_bf16(A0, Bf[1], Z, 0, 0, 0);
      f32x4 c11 = __builtin_amdgcn_mfma_f32_16x16x32_bf16(A1, Bf[1], Z, 0, 0, 0);
      f32x4 c12 = __builtin_amdgcn_mfma_f32_16x16x32_bf16(A2, Bf[1], Z, 0, 0, 0);
      f32x4 c13 = __builtin_amdgcn_mfma_f32_16x16x32_bf16(A3, Bf[1], Z, 0, 0, 0);
      lse_merge16(m0, s0_, c00, c01, c02, c03);
      lse_merge16(m1, s1_, c10, c11, c12, c13);
    }

    // ---- cross-quad merge + store partial ----
#pragma unroll
    for (int rs = 0; rs < 2; ++rs) {
      float m = rs ? m1 : m0;
      float s = rs ? s1_ : s0_;
#pragma unroll
      for (int off = 16; off <= 32; off <<= 1) {
        float mo = __shfl_xor(m, off, 64);
        float so = __shfl_xor(s, off, 64);
        float mn = fmaxf(m, mo);
        s = s * EXP2(m - mn) + so * EXP2(mo - mn);
        m = mn;
      }
      if (lane < 16) {
        int i = rowbase + rs * 16 + lane;
        Pcur[(tbl * 4 + part) * NPT + i] = make_float2(m, s);
      }
    }

    epsPrev = eps;
    if (L < NLAUNCH - 1)
      grid_barrier(A.bar, (unsigned)(GRID * (L + 1)));
  }
}

// reduce1: finalize last-iteration partials, per-row contribution, per-block partial sums
__global__ __launch_bounds__(256) void reduce1(const float2* P, float* R1) {
  int u = blockIdx.x * 256 + threadIdx.x;   // 0..8191
  int b = u >> 12, i = u & 4095;
  float Ls[4];
#pragma unroll
  for (int t = 0; t < 4; ++t) {
    int tbl = t * 2 + b;
    float2 q0 = P[(tbl * 4 + 0) * NPT + i];
    float2 q1 = P[(tbl * 4 + 1) * NPT + i];
    float2 q2 = P[(tbl * 4 + 2) * NPT + i];
    float2 q3 = P[(tbl * 4 + 3) * NPT + i];
    float M = fmaxf(fmaxf(q0.x, q1.x), fmaxf(q2.x, q3.x));
    float S = q0.y * EXP2(q0.x - M) + q1.y * EXP2(q1.x - M)
            + q2.y * EXP2(q2.x - M) + q3.y * EXP2(q3.x - M);
    Ls[t] = M + LOG2(S);
  }
  // (b_x - a_x) + (a_y - b_y) = -eps*ln2*((L0 - L2) + (L1 - L3))
  float acc = (Ls[0] - Ls[2]) + (Ls[1] - Ls[3]);
#pragma unroll
  for (int off = 32; off >= 1; off >>= 1) acc += __shfl_xor(acc, off, 64);
  __shared__ float red[4];
  int wave = threadIdx.x >> 6, lane = threadIdx.x & 63;
  if (lane == 0) red[wave] = acc;
  __syncthreads();
  if (threadIdx.x == 0)
    R1[blockIdx.x] = red[0] + red[1] + red[2] + red[3];
}

__global__ __launch_bounds__(64) void reduce2(const float* R1, float* out) {
  float a = (threadIdx.x < 32) ? R1[threadIdx.x] : 0.0f;
#pragma unroll
  for (int off = 32; off >= 1; off >>= 1) a += __shfl_xor(a, off, 64);
  if (threadIdx.x == 0)
    out[0] = a * (-0.0025f * KLN2 / 4096.0f);
}

extern "C" void kernel_launch(void* const* d_in, const int* in_sizes, int n_in,
                              void* d_out, int out_size, void* d_ws, size_t ws_size,
                              hipStream_t stream) {
  const float* x = (const float*)d_in[0];   // true_data
  const float* y = (const float*)d_in[1];   // particles
  float* out = (float*)d_out;
  float* W = (float*)d_ws;

  PArgs A;
  A.x = x;
  A.y = y;
  A.P0 = (float2*)W;                   // 1 MB
  A.P1 = (float2*)(W + 262144);        // 1 MB
  A.F0 = W + 524288;                   // 128 KB
  A.F1 = W + 557056;                   // 128 KB
  A.bar = (unsigned*)(W + 590080);
  float* R1buf = W + 589824;           // 32 floats

  hipMemsetAsync((void*)A.bar, 0, sizeof(unsigned), stream);

  softmin_persist<<<dim3(GRID), dim3(BLOCK), 0, stream>>>(A);

  // final iteration (L=10, even) wrote Pcur = P0
  reduce1<<<32, 256, 0, stream>>>(A.P0, R1buf);
  reduce2<<<1, 64, 0, stream>>>(R1buf, out);
}

// Round 5
// 323.463 us; speedup vs baseline: 1.7868x; 1.7868x over previous
//
#include <hip/hip_runtime.h>

// Sinkhorn divergence (geomloss 'sinkhorn', p=2, blur=0.05, diameter=4, scaling=0.5, debias)
// B=2, N=M=4096, D=3, fp32.
// R9: barrier rearchitecture. R8 counters: persist=540us, per-SIMD VALU ~9%, MFMA 7%,
// HBM 1% -> 85% idle; only new structure was the barrier. Diagnosis: 512 device-scope
// atomicAdds serializing on one line (~200cy each ~= 40us/barrier) + 2x512 threadfence
// L2 wb/inv per barrier. New barrier: arrival = per-block slot STORE (parallel, no RMW);
// root block 0 polls all 512 slots (one per thread, __syncthreads_and) then stores a
// release epoch; others spin-load release. NO atomicAdd, NO threadfence. Cross-iteration
// data (P/F) moves via agent-scope relaxed atomics (write/read through to coherence
// point, no L2 allocation -> no stale lines, no flush). All spins bounded.
// Carried from R8: plain launch (co-residency by construction: 2 blocks/CU x 256 = 512),
// hoisted B fragments + y loads, baseline inner loop (all-EXP2 merge16, 8 MFMAs/64 cols).

typedef __attribute__((ext_vector_type(8))) short short8;
typedef __attribute__((ext_vector_type(8))) __bf16 bf16x8;
typedef __attribute__((ext_vector_type(4))) float f32x4;
typedef __attribute__((ext_vector_type(2))) float f32x2;

#define NPT 4096
#define BLOCK 512
#define COLS 1024           // columns per block (one part)
#define GRID 512            // 8 tbl x 4 parts x 16 rowchunks
#define NLAUNCH 11
#define EXP2 __builtin_amdgcn_exp2f
#define LOG2 __builtin_amdgcn_logf
#define KLOG2E 1.4426950408889634f
#define KLN2 0.6931471805599453f

__device__ const float epsC[NLAUNCH] = {16.0f, 16.0f, 16.0f, 4.0f, 1.0f, 0.25f,
                                        0.0625f, 0.015625f, 0.00390625f, 0.0025f, 0.0025f};

__device__ inline unsigned short f2bf(float f) {
  unsigned u = __float_as_uint(f);
  return (unsigned short)((u + 0x7FFF + ((u >> 16) & 1)) >> 16);
}
__device__ inline float bf2f(unsigned short h) {
  return __uint_as_float(((unsigned)h) << 16);
}

// ---- agent-scope (device) data movement: goes to/from the coherent point, no L2 alloc
__device__ inline float2 ldP(const float2* p) {
  unsigned long long v = __hip_atomic_load((const unsigned long long*)p,
                                           __ATOMIC_RELAXED, __HIP_MEMORY_SCOPE_AGENT);
  return __builtin_bit_cast(float2, v);
}
__device__ inline void stP(float2* p, float2 f) {
  __hip_atomic_store((unsigned long long*)p, __builtin_bit_cast(unsigned long long, f),
                     __ATOMIC_RELAXED, __HIP_MEMORY_SCOPE_AGENT);
}
__device__ inline float ldF(const float* p) {
  unsigned v = __hip_atomic_load((const unsigned*)p, __ATOMIC_RELAXED,
                                 __HIP_MEMORY_SCOPE_AGENT);
  return __uint_as_float(v);
}
__device__ inline void stF(float* p, float f) {
  __hip_atomic_store((unsigned*)p, __float_as_uint(f), __ATOMIC_RELAXED,
                     __HIP_MEMORY_SCOPE_AGENT);
}

struct PArgs {
  const float* x;
  const float* y;
  float2* P0;   // partials buffer A [8 tbl][4 part][4096] (m,s)
  float2* P1;   // partials buffer B
  float* F0;    // finalized potentials buffer A [8 tbl][4096]
  float* F1;
  unsigned* slots;    // 512 per-block arrival epochs (zeroed per launch)
  unsigned* release;  // root-published release epoch
};

// Store/poll grid barrier. All 512 blocks co-resident. Epochs are monotonic (no ABA).
// Bounded polls turn any residual bug into a finite wrong answer, not a hang.
__device__ inline void grid_barrier(unsigned* slots, unsigned* release, unsigned epoch) {
  __syncthreads();   // all waves done; compiler drains vmcnt/lgkmcnt here
  if (threadIdx.x == 0)
    __hip_atomic_store(&slots[blockIdx.x], epoch, __ATOMIC_RELAXED,
                       __HIP_MEMORY_SCOPE_AGENT);
  if (blockIdx.x == 0) {
    // root: 512 threads poll 512 slots
    unsigned spins = 0;
    int ok;
    do {
      unsigned v = __hip_atomic_load(&slots[threadIdx.x], __ATOMIC_RELAXED,
                                     __HIP_MEMORY_SCOPE_AGENT);
      ok = (v >= epoch) || (spins > (1u << 20));
      if (!ok) __builtin_amdgcn_s_sleep(1);
      ++spins;
    } while (!__syncthreads_and(ok));
    if (threadIdx.x == 0)
      __hip_atomic_store(release, epoch, __ATOMIC_RELAXED, __HIP_MEMORY_SCOPE_AGENT);
    __syncthreads();
  } else {
    if (threadIdx.x == 0) {
      unsigned spins = 0;
      while (__hip_atomic_load(release, __ATOMIC_RELAXED,
                               __HIP_MEMORY_SCOPE_AGENT) < epoch) {
        __builtin_amdgcn_s_sleep(2);
        if (++spins > (1u << 22)) break;   // safety valve
      }
    }
    __syncthreads();   // also a compiler memory barrier: no load hoisting above spin
  }
}

// merge 16 values into running (m,s); max3-friendly tree + packed f32x2 sub/sum.
__device__ inline void lse_merge16(float& m, float& s,
                                   f32x4 c0, f32x4 c1, f32x4 c2, f32x4 c3) {
  float t0 = fmaxf(fmaxf(c0.x, c0.y), c0.z);
  float t1 = fmaxf(fmaxf(c0.w, c1.x), c1.y);
  float t2 = fmaxf(fmaxf(c1.z, c1.w), c2.x);
  float t3 = fmaxf(fmaxf(c2.y, c2.z), c2.w);
  float t4 = fmaxf(fmaxf(c3.x, c3.y), c3.z);
  float u0 = fmaxf(fmaxf(t0, t1), c3.w);
  float u1 = fmaxf(fmaxf(t2, t3), t4);
  float cm = fmaxf(u0, u1);
  float mn = fmaxf(m, cm);
  float sc = EXP2(m - mn);                 // m=-inf first iter -> 0
  f32x2 mn2 = {mn, mn};
  f32x2 sa = {0.0f, 0.0f}, sb = {0.0f, 0.0f};
  f32x2 d;
  d = (f32x2){c0.x, c0.y} - mn2; sa += (f32x2){EXP2(d.x), EXP2(d.y)};
  d = (f32x2){c0.z, c0.w} - mn2; sb += (f32x2){EXP2(d.x), EXP2(d.y)};
  d = (f32x2){c1.x, c1.y} - mn2; sa += (f32x2){EXP2(d.x), EXP2(d.y)};
  d = (f32x2){c1.z, c1.w} - mn2; sb += (f32x2){EXP2(d.x), EXP2(d.y)};
  d = (f32x2){c2.x, c2.y} - mn2; sa += (f32x2){EXP2(d.x), EXP2(d.y)};
  d = (f32x2){c2.z, c2.w} - mn2; sb += (f32x2){EXP2(d.x), EXP2(d.y)};
  d = (f32x2){c3.x, c3.y} - mn2; sa += (f32x2){EXP2(d.x), EXP2(d.y)};
  d = (f32x2){c3.z, c3.w} - mn2; sb += (f32x2){EXP2(d.x), EXP2(d.y)};
  sa += sb;
  s = fmaf(s, sc, sa.x + sa.y);
  m = mn;
}

__global__ __launch_bounds__(BLOCK, 4) void softmin_persist(PArgs A) {
  __shared__ short8 fragA0[COLS];   // k0..7  per column
  __shared__ short8 fragA1[COLS];   // k8..15 per column

  const int bid  = blockIdx.x;
  const int tbl  = bid >> 6;          // 0..7 = task*2+batch
  const int task = tbl >> 1, batch = tbl & 1;
  const int rem  = bid & 63;
  const int part = rem >> 4;
  const int rc   = rem & 15;

  // rows[4]={x,y,x,y}; cols[4]={y,x,x,y}
  const bool rowIsX = (task == 0) | (task == 2);
  const bool colIsX = (task == 1) | (task == 2);
  const float* xp = (rowIsX ? A.x : A.y) + batch * NPT * 3;
  const float* yp = (colIsX ? A.x : A.y) + batch * NPT * 3;

  const float hc = -8.317766166719343f;   // -ln(4096)
  const int pidxA[4] = {1, 0, 2, 3};
  const int tP = pidxA[task] * 2 + batch;

  const int lane = threadIdx.x & 63;
  const int wave = threadIdx.x >> 6;
  const int q    = lane >> 4;
  const int rowbase = rc * 256 + wave * 32;

  // ---- B fragments (row side): eps-independent, build ONCE ----
  bf16x8 Bf[2];
#pragma unroll
  for (int rs = 0; rs < 2; ++rs) {
    int i = rowbase + rs * 16 + (lane & 15);
    float X0 = xp[3 * i], X1 = xp[3 * i + 1], X2 = xp[3 * i + 2];
    unsigned short xh0 = f2bf(X0), xh1 = f2bf(X1), xh2 = f2bf(X2);
    unsigned short xl0 = f2bf(X0 - bf2f(xh0));
    unsigned short xl1 = f2bf(X1 - bf2f(xh1));
    unsigned short xl2 = f2bf(X2 - bf2f(xh2));
    short8 bb = (short8)0;
    if (q == 0) {
      short8 t = {(short)xh0, (short)xh1, (short)xh2,
                  (short)xh0, (short)xh1, (short)xh2,
                  (short)xl0, (short)xl1};
      bb = t;
    } else if (q == 1) {
      short8 t = {(short)xl2, (short)0x3F80, (short)0x3F80, (short)0x3F80,
                  (short)xl0, (short)xl1, (short)xl2, 0};
      bb = t;
    }
    Bf[rs] = __builtin_bit_cast(bf16x8, bb);
  }

  // ---- per-thread column data: load ONCE, keep in registers ----
  float Y0[2], Y1[2], Y2[2], Y2N[2];
#pragma unroll
  for (int c = 0; c < 2; ++c) {
    int j = part * COLS + threadIdx.x + c * BLOCK;
    Y0[c] = yp[3 * j]; Y1[c] = yp[3 * j + 1]; Y2[c] = yp[3 * j + 2];
    Y2N[c] = 0.5f * (Y0[c] * Y0[c] + Y1[c] * Y1[c] + Y2[c] * Y2[c]);
  }

  float epsPrev = 1.0f;
  for (int L = 0; L < NLAUNCH; ++L) {
    const float eps = epsC[L];
    const int usePot  = (L >= 1);
    const int avgPrev = (L >= 2);
    const float2* Pprev = (L & 1) ? A.P0 : A.P1;
    float2*       Pcur  = (L & 1) ? A.P1 : A.P0;
    const float*  Fprev = (L & 1) ? A.F0 : A.F1;
    float*        Fcur  = (L & 1) ? A.F1 : A.F0;
    const float inv_eps = 1.0f / eps;
    const float sY = inv_eps * KLOG2E;

    // ---- staging: finalize prev-iteration potentials + build column A-fragments ----
#pragma unroll
    for (int c = 0; c < 2; ++c) {
      int jl = threadIdx.x + c * BLOCK;
      int j  = part * COLS + jl;
      float y0 = Y0[c], y1 = Y1[c], y2 = Y2[c];
      float y2n = Y2N[c];
      float pot = 0.0f;
      if (usePot) {
        float2 q0 = ldP(&Pprev[(tP * 4 + 0) * NPT + j]);
        float2 q1 = ldP(&Pprev[(tP * 4 + 1) * NPT + j]);
        float2 q2 = ldP(&Pprev[(tP * 4 + 2) * NPT + j]);
        float2 q3 = ldP(&Pprev[(tP * 4 + 3) * NPT + j]);
        float M = fmaxf(fmaxf(q0.x, q1.x), fmaxf(q2.x, q3.x));
        float S = q0.y * EXP2(q0.x - M) + q1.y * EXP2(q1.x - M)
                + q2.y * EXP2(q2.x - M) + q3.y * EXP2(q3.x - M);
        float Lg = M + LOG2(S);
        float r = y2n - epsPrev * KLN2 * Lg;
        if (avgPrev) r = 0.5f * (ldF(&Fprev[tP * NPT + j]) + r);
        pot = r;
        if (rc == 0) stF(&Fcur[tP * NPT + j], pot);
      }
      float T = (hc + (pot - y2n) * inv_eps) * KLOG2E;
      float s0 = y0 * sY, s1 = y1 * sY, s2 = y2 * sY;
      unsigned short yh0 = f2bf(s0), yh1 = f2bf(s1), yh2 = f2bf(s2);
      unsigned short yl0 = f2bf(s0 - bf2f(yh0));
      unsigned short yl1 = f2bf(s1 - bf2f(yh1));
      unsigned short yl2 = f2bf(s2 - bf2f(yh2));
      unsigned short Th = f2bf(T);
      float tr = T - bf2f(Th);
      unsigned short Tm = f2bf(tr);
      tr -= bf2f(Tm);
      unsigned short Tl = f2bf(tr);
      short8 h0 = {(short)yh0, (short)yh1, (short)yh2,
                   (short)yl0, (short)yl1, (short)yl2,
                   (short)yh0, (short)yh1};
      short8 h1 = {(short)yh2, (short)Th, (short)Tm, (short)Tl,
                   (short)yl0, (short)yl1, (short)yl2, 0};
      fragA0[jl] = h0;
      fragA1[jl] = h1;
    }
    __syncthreads();

    // ---- inner loop: 4 column tiles (64 cols) per iteration, 8 MFMAs ----
    const short8* srcA = (lane & 16) ? fragA1 : fragA0;
    const int colsel = lane & 15;
    const f32x4 Z = {0.0f, 0.0f, 0.0f, 0.0f};
    short8 as0 = (short8)0, as1 = (short8)0, as2 = (short8)0, as3 = (short8)0;
    float m0 = -__builtin_inff(), s0_ = 0.0f;
    float m1 = -__builtin_inff(), s1_ = 0.0f;

    for (int jt = 0; jt < COLS / 16; jt += 4) {
      if (lane < 32) {
        as0 = srcA[(jt + 0) * 16 + colsel];
        as1 = srcA[(jt + 1) * 16 + colsel];
        as2 = srcA[(jt + 2) * 16 + colsel];
        as3 = srcA[(jt + 3) * 16 + colsel];
      }
      bf16x8 A0 = __builtin_bit_cast(bf16x8, as0);
      bf16x8 A1 = __builtin_bit_cast(bf16x8, as1);
      bf16x8 A2 = __builtin_bit_cast(bf16x8, as2);
      bf16x8 A3 = __builtin_bit_cast(bf16x8, as3);
      f32x4 c00 = __builtin_amdgcn_mfma_f32_16x16x32_bf16(A0, Bf[0], Z, 0, 0, 0);
      f32x4 c01 = __builtin_amdgcn_mfma_f32_16x16x32_bf16(A1, Bf[0], Z, 0, 0, 0);
      f32x4 c02 = __builtin_amdgcn_mfma_f32_16x16x32_bf16(A2, Bf[0], Z, 0, 0, 0);
      f32x4 c03 = __builtin_amdgcn_mfma_f32_16x16x32_bf16(A3, Bf[0], Z, 0, 0, 0);
      f32x4 c10 = __builtin_amdgcn_mfma_f32_16x16x32_bf16(A0, Bf[1], Z, 0, 0, 0);
      f32x4 c11 = __builtin_amdgcn_mfma_f32_16x16x32_bf16(A1, Bf[1], Z, 0, 0, 0);
      f32x4 c12 = __builtin_amdgcn_mfma_f32_16x16x32_bf16(A2, Bf[1], Z, 0, 0, 0);
      f32x4 c13 = __builtin_amdgcn_mfma_f32_16x16x32_bf16(A3, Bf[1], Z, 0, 0, 0);
      lse_merge16(m0, s0_, c00, c01, c02, c03);
      lse_merge16(m1, s1_, c10, c11, c12, c13);
    }

    // ---- cross-quad merge + store partial (agent-scope) ----
#pragma unroll
    for (int rs = 0; rs < 2; ++rs) {
      float m = rs ? m1 : m0;
      float s = rs ? s1_ : s0_;
#pragma unroll
      for (int off = 16; off <= 32; off <<= 1) {
        float mo = __shfl_xor(m, off, 64);
        float so = __shfl_xor(s, off, 64);
        float mn = fmaxf(m, mo);
        s = s * EXP2(m - mn) + so * EXP2(mo - mn);
        m = mn;
      }
      if (lane < 16) {
        int i = rowbase + rs * 16 + lane;
        stP(&Pcur[(tbl * 4 + part) * NPT + i], make_float2(m, s));
      }
    }

    epsPrev = eps;
    if (L < NLAUNCH - 1)
      grid_barrier(A.slots, A.release, (unsigned)(L + 1));
  }
}

// reduce1: finalize last-iteration partials, per-row contribution, per-block partial sums
__global__ __launch_bounds__(256) void reduce1(const float2* P, float* R1) {
  int u = blockIdx.x * 256 + threadIdx.x;   // 0..8191
  int b = u >> 12, i = u & 4095;
  float Ls[4];
#pragma unroll
  for (int t = 0; t < 4; ++t) {
    int tbl = t * 2 + b;
    float2 q0 = P[(tbl * 4 + 0) * NPT + i];
    float2 q1 = P[(tbl * 4 + 1) * NPT + i];
    float2 q2 = P[(tbl * 4 + 2) * NPT + i];
    float2 q3 = P[(tbl * 4 + 3) * NPT + i];
    float M = fmaxf(fmaxf(q0.x, q1.x), fmaxf(q2.x, q3.x));
    float S = q0.y * EXP2(q0.x - M) + q1.y * EXP2(q1.x - M)
            + q2.y * EXP2(q2.x - M) + q3.y * EXP2(q3.x - M);
    Ls[t] = M + LOG2(S);
  }
  // (b_x - a_x) + (a_y - b_y) = -eps*ln2*((L0 - L2) + (L1 - L3))
  float acc = (Ls[0] - Ls[2]) + (Ls[1] - Ls[3]);
#pragma unroll
  for (int off = 32; off >= 1; off >>= 1) acc += __shfl_xor(acc, off, 64);
  __shared__ float red[4];
  int wave = threadIdx.x >> 6, lane = threadIdx.x & 63;
  if (lane == 0) red[wave] = acc;
  __syncthreads();
  if (threadIdx.x == 0)
    R1[blockIdx.x] = red[0] + red[1] + red[2] + red[3];
}

__global__ __launch_bounds__(64) void reduce2(const float* R1, float* out) {
  float a = (threadIdx.x < 32) ? R1[threadIdx.x] : 0.0f;
#pragma unroll
  for (int off = 32; off >= 1; off >>= 1) a += __shfl_xor(a, off, 64);
  if (threadIdx.x == 0)
    out[0] = a * (-0.0025f * KLN2 / 4096.0f);
}

extern "C" void kernel_launch(void* const* d_in, const int* in_sizes, int n_in,
                              void* d_out, int out_size, void* d_ws, size_t ws_size,
                              hipStream_t stream) {
  const float* x = (const float*)d_in[0];   // true_data
  const float* y = (const float*)d_in[1];   // particles
  float* out = (float*)d_out;
  float* W = (float*)d_ws;

  PArgs A;
  A.x = x;
  A.y = y;
  A.P0 = (float2*)W;                   // 1 MB
  A.P1 = (float2*)(W + 262144);        // 1 MB
  A.F0 = W + 524288;                   // 128 KB
  A.F1 = W + 557056;                   // 128 KB
  float* R1buf = W + 589824;           // 32 floats
  A.slots   = (unsigned*)(W + 590080); // 512 u32
  A.release = (unsigned*)(W + 590592); // 1 u32

  hipMemsetAsync((void*)A.slots, 0, 513 * sizeof(unsigned), stream);

  softmin_persist<<<dim3(GRID), dim3(BLOCK), 0, stream>>>(A);

  // final iteration (L=10, even) wrote Pcur = P0
  reduce1<<<32, 256, 0, stream>>>(A.P0, R1buf);
  reduce2<<<1, 64, 0, stream>>>(R1buf, out);
}